// Round 16
// baseline (98.539 us; speedup 1.0000x reference)
//
#include <hip/hip_runtime.h>
#include <stdint.h>

// PlaceCellNetwork — 50 fixed-point Jacobi iterations, per-row independent.
//
// R16: swap v_mfma_f32_16x16x16f16 -> v_mfma_f32_16x16x32_f16.
//
// R14 counter arithmetic: MfmaUtil 40% = 100k matrix-cycles/SIMD for 5978
// MFMAs/SIMD => ~16.7 cyc per legacy 16x16x16 MFMA. The gfx950-native
// 16x16x32 family measures ~4.85 cyc (m06/m119). The loop is matrix-pipe
// bound on the slow instruction; VALU-only is ~21%.
//
// K=32 with 22 provably-zero slots, NO cross-lane repack, via K-permutation:
//   kin: k0..3 -> z0..3, k8..11 -> z4..7, k16..17 -> z8..9, else zero.
// B layout (16x16x32): lane = n + 16*(k/8), elem = k%8 (4 VGPRs).
// D layout (16x16 family, K-independent): col = lane&15, row = (lane>>4)*4+e.
// Lane-group g computes z'_{4g..4g+3} (2 u32 words Blo/Bhi) and its B slots
// k=8g..8g+7 want exactly those values in elems 0..3 (grp2: elems 0,1; its
// Bhi is exactly 0 since A rows m>=10 and c j>=10 are zeroed; grp3 all 0).
// => B = {Blo, Bhi, 0, 0} UNIVERSALLY. A absorbs the permutation at build:
//   A[m][k=8q+e] = G[kin(k)][m], q = lane>>4.
//
// Everything else identical to R15 (PASSED, absmax 0.125): c as C operand,
// iter 1 free (z1=relu(c)), final iter in f32 for the store, Y_j = rd_j*z_j.

typedef _Float16 h2 __attribute__((ext_vector_type(2)));
typedef _Float16 h8 __attribute__((ext_vector_type(8)));
typedef float    f4 __attribute__((ext_vector_type(4)));
typedef uint32_t u32;
typedef uint32_t u32x4 __attribute__((ext_vector_type(4)));

constexpr int IN_DIM  = 5;
constexpr int OUT_DIM = 10;
constexpr int ITERS   = 50;
constexpr int NT      = 4;              // tiles per wave
constexpr float DT = 0.05f, LBD1 = 0.005f, LBD2 = 0.005f;

#if defined(__HIP_DEVICE_COMPILE__)
  #if __has_builtin(__builtin_amdgcn_mfma_f32_16x16x32_f16)
    #define MFMA32(a, b, c) __builtin_amdgcn_mfma_f32_16x16x32_f16((a), (b), (c), 0, 0, 0)
  #elif __has_builtin(__builtin_amdgcn_mfma_f32_16x16x32f16)
    #define MFMA32(a, b, c) __builtin_amdgcn_mfma_f32_16x16x32f16((a), (b), (c), 0, 0, 0)
  #else
    #error "no 16x16x32 f16 MFMA builtin on device"
  #endif
#else
  #define MFMA32(a, b, c) (c)           // host pass: parse-only
#endif

__device__ __forceinline__ u32 cvt_relu_pk(float a, float b) {
    // v_cvt_pkrtz_f16_f32 + v_pk_max_f16 -> one 32-bit word (2 f16 lanes)
    h2 v = __builtin_bit_cast(h2, __builtin_amdgcn_cvt_pkrtz(a, b));
    h2 z; z.x = (_Float16)0.0f; z.y = (_Float16)0.0f;
    return __builtin_bit_cast(u32, __builtin_elementwise_max(v, z));
}

__global__ __launch_bounds__(256, 4) void pcn_kernel(
    const float* __restrict__ X,    // [n, 5]
    const float* __restrict__ W,    // [10, 5]
    const float* __restrict__ Mg,   // [10, 10]
    const float* __restrict__ b,    // [10]
    float* __restrict__ out,        // [n, 10]
    int n)
{
    __shared__ float gtab[100];     // G[k][j]
    __shared__ float rdtab[OUT_DIM];

    const int tid = threadIdx.x;
    if (tid < 100) {
        int k = tid / 10, j = tid % 10;
        float rdk = 1.0f / (LBD2 + Mg[k * 10 + k]);
        float rdj = 1.0f / (LBD2 + Mg[j * 10 + j]);
        gtab[tid] = (k == j) ? (1.0f - DT) * rdj : -DT * rdk * Mg[k * 10 + j];
        if (tid < OUT_DIM) rdtab[tid] = rdj;
    }
    __syncthreads();

    const int lane = tid & 63;
    const int w    = tid >> 6;      // wave in block (0..3)
    const int grp  = lane >> 4;     // K-block / D-row group (0..3)
    const int r16  = lane & 15;     // batch row within tile (N index)
    const int base = blockIdx.x * (64 * NT) + w * (16 * NT);

    // ---- A fragment (16x16x32): lane holds A[m=r16][k=8*grp+e], e=0..7 ----
    // kin: grp0 e<4 -> G row e; grp1 e<4 -> G row 4+e; grp2 e<2 -> G row 8+e.
    h8 afrag;
#pragma unroll
    for (int e = 0; e < 8; ++e) {
        int kk = -1;
        if (grp == 0 && e < 4) kk = e;
        else if (grp == 1 && e < 4) kk = 4 + e;
        else if (grp == 2 && e < 2) kk = 8 + e;
        float g = (kk >= 0 && r16 < OUT_DIM) ? gtab[kk * 10 + r16] : 0.0f;
        afrag[e] = (_Float16)g;
    }

    // ---- per-lane epilogue scales (D row m = grp*4+e) ----
    float rdv[4];
#pragma unroll
    for (int e = 0; e < 4; ++e) {
        int j = grp * 4 + e;
        rdv[e] = (j < OUT_DIM) ? rdtab[j] : 0.0f;
    }

    // ---- per-tile c fragments (C operand) ----
    f4 cf[NT];
#pragma unroll
    for (int t = 0; t < NT; ++t) {
        int r = base + t * 16 + r16;
        float x[IN_DIM];
        if (r < n) {
#pragma unroll
            for (int d = 0; d < IN_DIM; ++d) x[d] = X[r * IN_DIM + d];
        } else {
#pragma unroll
            for (int d = 0; d < IN_DIM; ++d) x[d] = 0.0f;
        }
#pragma unroll
        for (int e = 0; e < 4; ++e) {
            int j = grp * 4 + e;
            if (j < OUT_DIM) {
                float s = -b[j];
#pragma unroll
                for (int d = 0; d < IN_DIM; ++d) s = fmaf(x[d], W[j * IN_DIM + d], s);
                cf[t][e] = fmaf(DT, s, -LBD1);
            } else {
                cf[t][e] = 0.0f;    // keeps padded D rows (and grp2 Bhi) exactly 0
            }
        }
    }

    // ---- iteration 1 free: z1 = relu(c) ----
    u32 Blo[NT], Bhi[NT];
#pragma unroll
    for (int t = 0; t < NT; ++t) {
        Blo[t] = cvt_relu_pk(cf[t][0], cf[t][1]);
        Bhi[t] = cvt_relu_pk(cf[t][2], cf[t][3]);
    }

    // ---- iterations 2..49: B = {Blo, Bhi, 0, 0} for every lane ----
#pragma unroll 2
    for (int it = 0; it < ITERS - 2; ++it) {
#pragma unroll
        for (int t = 0; t < NT; ++t) {
            u32x4 bw; bw.x = Blo[t]; bw.y = Bhi[t]; bw.z = 0u; bw.w = 0u;
            f4 acc = MFMA32(afrag, __builtin_bit_cast(h8, bw), cf[t]);
            Blo[t] = cvt_relu_pk(acc[0], acc[1]);
            Bhi[t] = cvt_relu_pk(acc[2], acc[3]);
        }
    }

    // ---- iteration 50 in f32 + scaled store: Y[r][j] = rd_j * z_j ----
#pragma unroll
    for (int t = 0; t < NT; ++t) {
        u32x4 bw; bw.x = Blo[t]; bw.y = Bhi[t]; bw.z = 0u; bw.w = 0u;
        f4 acc = MFMA32(afrag, __builtin_bit_cast(h8, bw), cf[t]);
        int r = base + t * 16 + r16;
        if (r < n) {
            float y0 = fmaxf(acc[0], 0.0f) * rdv[0];
            float y1 = fmaxf(acc[1], 0.0f) * rdv[1];
            float y2 = fmaxf(acc[2], 0.0f) * rdv[2];
            float y3 = fmaxf(acc[3], 0.0f) * rdv[3];
            float* o = out + r * OUT_DIM + grp * 4;
            if (grp < 2) {                    // j 0-3 / 4-7
                *(float2*)(o)     = make_float2(y0, y1);
                *(float2*)(o + 2) = make_float2(y2, y3);
            } else if (grp == 2) {            // j 8-9
                *(float2*)(o)     = make_float2(y0, y1);
            }                                  // grp==3: nothing
        }
    }
}

extern "C" void kernel_launch(void* const* d_in, const int* in_sizes, int n_in,
                              void* d_out, int out_size, void* d_ws, size_t ws_size,
                              hipStream_t stream) {
    const float* X = (const float*)d_in[0];
    const float* W = (const float*)d_in[1];
    const float* M = (const float*)d_in[2];
    const float* b = (const float*)d_in[3];
    float* out = (float*)d_out;

    int n = in_sizes[0] / IN_DIM;           // 500000 rows
    int rows_per_block = 64 * NT;           // 4 waves x 4 tiles x 16 rows = 256
    int grid = (n + rows_per_block - 1) / rows_per_block;
    pcn_kernel<<<grid, 256, 0, stream>>>(X, W, M, b, out, n);
}

// Round 17
// 90.789 us; speedup vs baseline: 1.0854x; 1.0854x over previous
//
#include <hip/hip_runtime.h>
#include <stdint.h>

// PlaceCellNetwork — 50 fixed-point Jacobi iterations, per-row independent.
//
// R17 = R15 (16x16x16 form — best bench 92.4/91.7 family) + grid doubling.
//
// R16 post-mortem: K=32 swap (3x fewer matrix-pipe cycles) was NEUTRAL-to-
// worse => matrix pipe (40% busy) was never the bound. R14's counter triad
// (MFMA 40 / VALU 61 / Occ 53, nothing saturated) = latency-bound. Root
// cause found: grid = 1954 blocks = 7.6 blocks/CU < the 8 needed for full
// 32 waves/CU — the machine cannot reach full TLP, and there's no second
// generation to backfill. Fix: NT=2 -> 3907 blocks = 15.2 blocks/CU ->
// occupancy saturates (8 blocks/CU resident + backfill generation).
// Same instruction count, 2x thread-level parallelism.
//
// Formulation (PASSED since R11, absmax 0.125): z' = relu(G^T z + c) as
// v_mfma_f32_16x16x16f16; M=output j (10/16), N=rows (16/tile), K=state k.
//   A[m][k]=G[k][m]: lane = m + 16*(k/4), elem = k%4
//   B[k][n]:         lane = n + 16*(k/4), elem = k%4
//   D[m][n]:         lane = n + 16*(m/4), elem = m%4  (== B's mapping)
// => D -> cvt_pkrtz -> v_pk_max -> next B, zero cross-lane movement.
// B kept as two u32 words straight from cvt_relu_pk. Iter 1 free
// (z1=relu(c)); final iter in f32 for the store; Y_j = rd_j*z_j.

typedef _Float16 h2 __attribute__((ext_vector_type(2)));
typedef _Float16 h4 __attribute__((ext_vector_type(4)));
typedef float    f4 __attribute__((ext_vector_type(4)));
typedef uint32_t u32;

constexpr int IN_DIM  = 5;
constexpr int OUT_DIM = 10;
constexpr int ITERS   = 50;
constexpr int NT      = 2;              // tiles per wave (32 rows/wave)
constexpr float DT = 0.05f, LBD1 = 0.005f, LBD2 = 0.005f;

#if defined(__HIP_DEVICE_COMPILE__)
  #define MFMA16(a, b, c) __builtin_amdgcn_mfma_f32_16x16x16f16((a), (b), (c), 0, 0, 0)
#else
  #define MFMA16(a, b, c) (c)           // host pass: parse-only
#endif

__device__ __forceinline__ u32 cvt_relu_pk(float a, float b) {
    // v_cvt_pkrtz_f16_f32 + v_pk_max_f16 -> one 32-bit word (2 f16 lanes)
    h2 v = __builtin_bit_cast(h2, __builtin_amdgcn_cvt_pkrtz(a, b));
    h2 z; z.x = (_Float16)0.0f; z.y = (_Float16)0.0f;
    return __builtin_bit_cast(u32, __builtin_elementwise_max(v, z));
}

__global__ __launch_bounds__(256, 4) void pcn_kernel(
    const float* __restrict__ X,    // [n, 5]
    const float* __restrict__ W,    // [10, 5]
    const float* __restrict__ Mg,   // [10, 10]
    const float* __restrict__ b,    // [10]
    float* __restrict__ out,        // [n, 10]
    int n)
{
    __shared__ float gtab[100];     // G[k][j]
    __shared__ float rdtab[OUT_DIM];

    const int tid = threadIdx.x;
    if (tid < 100) {
        int k = tid / 10, j = tid % 10;
        float rdk = 1.0f / (LBD2 + Mg[k * 10 + k]);
        float rdj = 1.0f / (LBD2 + Mg[j * 10 + j]);
        gtab[tid] = (k == j) ? (1.0f - DT) * rdj : -DT * rdk * Mg[k * 10 + j];
        if (tid < OUT_DIM) rdtab[tid] = rdj;
    }
    __syncthreads();

    const int lane = tid & 63;
    const int w    = tid >> 6;      // wave in block (0..3)
    const int grp  = lane >> 4;     // element group (0..3)
    const int r16  = lane & 15;     // batch row within tile (N index)
    const int base = blockIdx.x * (64 * NT) + w * (16 * NT);

    // ---- A fragment: A[m][k] = G[k][m]; lane m=r16, k=grp*4+e ----
    h4 afrag;
#pragma unroll
    for (int e = 0; e < 4; ++e) {
        int k = grp * 4 + e;
        float g = (k < OUT_DIM && r16 < OUT_DIM) ? gtab[k * 10 + r16] : 0.0f;
        afrag[e] = (_Float16)g;
    }

    // ---- per-lane epilogue scales (D row m = grp*4+e) ----
    float rdv[4];
#pragma unroll
    for (int e = 0; e < 4; ++e) {
        int j = grp * 4 + e;
        rdv[e] = (j < OUT_DIM) ? rdtab[j] : 0.0f;
    }

    // ---- per-tile c fragments (C operand) ----
    f4 cf[NT];
#pragma unroll
    for (int t = 0; t < NT; ++t) {
        int r = base + t * 16 + r16;
        float x[IN_DIM];
        if (r < n) {
#pragma unroll
            for (int d = 0; d < IN_DIM; ++d) x[d] = X[r * IN_DIM + d];
        } else {
#pragma unroll
            for (int d = 0; d < IN_DIM; ++d) x[d] = 0.0f;
        }
#pragma unroll
        for (int e = 0; e < 4; ++e) {
            int j = grp * 4 + e;
            if (j < OUT_DIM) {
                float s = -b[j];
#pragma unroll
                for (int d = 0; d < IN_DIM; ++d) s = fmaf(x[d], W[j * IN_DIM + d], s);
                cf[t][e] = fmaf(DT, s, -LBD1);
            } else {
                cf[t][e] = 0.0f;    // padding stays exactly 0
            }
        }
    }

    // ---- iteration 1 free: z1 = relu(c) ----
    u32 Blo[NT], Bhi[NT];
#pragma unroll
    for (int t = 0; t < NT; ++t) {
        Blo[t] = cvt_relu_pk(cf[t][0], cf[t][1]);
        Bhi[t] = cvt_relu_pk(cf[t][2], cf[t][3]);
    }

    // ---- iterations 2..49 ----
#pragma unroll 2
    for (int it = 0; it < ITERS - 2; ++it) {
#pragma unroll
        for (int t = 0; t < NT; ++t) {
            uint2 bw; bw.x = Blo[t]; bw.y = Bhi[t];
            f4 acc = MFMA16(afrag, __builtin_bit_cast(h4, bw), cf[t]);
            Blo[t] = cvt_relu_pk(acc[0], acc[1]);
            Bhi[t] = cvt_relu_pk(acc[2], acc[3]);
        }
    }

    // ---- iteration 50 in f32 + scaled store: Y[r][j] = rd_j * z_j ----
#pragma unroll
    for (int t = 0; t < NT; ++t) {
        uint2 bw; bw.x = Blo[t]; bw.y = Bhi[t];
        f4 acc = MFMA16(afrag, __builtin_bit_cast(h4, bw), cf[t]);
        int r = base + t * 16 + r16;
        if (r < n) {
            float y0 = fmaxf(acc[0], 0.0f) * rdv[0];
            float y1 = fmaxf(acc[1], 0.0f) * rdv[1];
            float y2 = fmaxf(acc[2], 0.0f) * rdv[2];
            float y3 = fmaxf(acc[3], 0.0f) * rdv[3];
            float* o = out + r * OUT_DIM + grp * 4;
            if (grp < 2) {                    // j 0-3 / 4-7
                *(float2*)(o)     = make_float2(y0, y1);
                *(float2*)(o + 2) = make_float2(y2, y3);
            } else if (grp == 2) {            // j 8-9
                *(float2*)(o)     = make_float2(y0, y1);
            }                                  // grp==3: nothing
        }
    }
}

extern "C" void kernel_launch(void* const* d_in, const int* in_sizes, int n_in,
                              void* d_out, int out_size, void* d_ws, size_t ws_size,
                              hipStream_t stream) {
    const float* X = (const float*)d_in[0];
    const float* W = (const float*)d_in[1];
    const float* M = (const float*)d_in[2];
    const float* b = (const float*)d_in[3];
    float* out = (float*)d_out;

    int n = in_sizes[0] / IN_DIM;           // 500000 rows
    int rows_per_block = 64 * NT;           // 4 waves x 2 tiles x 16 rows = 128
    int grid = (n + rows_per_block - 1) / rows_per_block;   // 3907 blocks
    pcn_kernel<<<grid, 256, 0, stream>>>(X, W, M, b, out, n);
}